// Round 2
// 1187.606 us; speedup vs baseline: 1.1973x; 1.1973x over previous
//
#include <hip/hip_runtime.h>
#include <math.h>

#define CCH 512
#define HW 4096
#define NN 32768
#define NE 8192

// ws layout (bytes)
#define WS_BT  0                         // BT bf16 hi-only fragment-order: 8192*512*2B = 8388608
#define WS_ZZ  (8388608)                 // zz f32 [32768]
#define WS_BM1 (WS_ZZ + 131072)          // blockmax v1 [32768][64] f32 = 8388608
#define WS_BM2 (WS_BM1 + 8388608)        // blockmax v2 [32768][64] f32
#define WS_BI1 (WS_BM2 + 8388608)        // blockmax i1 [32768][64] i32
#define WS_IDX (WS_BI1 + 8388608)        // final idx [32768] i32
#define WS_ACC (WS_IDX + 131072)         // accs[0]=loss num, accs[1]=wsum (f64)

// bf16-only GEMM: score error std ~2e-5 (sigma_s ~3.2e-3, rel ~0.0064).
// THRESH=1e-3 = ~50 sigma guard; exact-fp32 rescan catches everything within it.
#define THRESH 1.0e-3f

typedef __attribute__((ext_vector_type(8)))  short short8;   // 8 bf16 (4 VGPRs)
typedef __attribute__((ext_vector_type(16))) float f32x16;   // 32x32 MFMA acc

// ---------------- K0: cb -> BT bf16 hi-only, fragment-linear layout; zero accs
// chunk(jt32, s): 64 lanes x 16B; lane l holds cb[j=jt*32+(l&31)][k=s*16+(l>>5)*8 + e], e=0..7
__global__ __launch_bounds__(256) void k_prep_b(const float* __restrict__ cb,
                                                unsigned short* __restrict__ BT,
                                                double* __restrict__ accs) {
    int t = blockIdx.x * 256 + threadIdx.x;
    if (t == 0) { accs[0] = 0.0; accs[1] = 0.0; }
    int l = t & 63, s = (t >> 6) & 31, jt = t >> 11;
    int j = jt * 32 + (l & 31);
    int kb = s * 16 + (l >> 5) * 8;
    short8 hv;
#pragma unroll
    for (int e = 0; e < 8; ++e) {
        float x = cb[(size_t)j * CCH + kb + e];
        hv[e] = (short)(__float_as_uint(x) >> 16);   // truncation to bf16
    }
    size_t chunk = (size_t)jt * 32 + s;
    *(short8*)&BT[chunk * 512 + (size_t)l * 8] = hv;
}

// ---------------- K1: zz[n] = np.sum(zf*zf, axis=1), numpy's exact pairwise tree
__global__ __launch_bounds__(256) void k_zz(const float* __restrict__ z,
                                            float* __restrict__ zz) {
    int t = threadIdx.x;
    int n = blockIdx.x * 256 + t;
    int b = n >> 12, hw = n & 4095;
    const float* zp = z + (size_t)b * CCH * HW + hw;
    float blk[4];
#pragma unroll
    for (int q = 0; q < 4; ++q) {
        float r[8];
#pragma unroll
        for (int j = 0; j < 8; ++j) {
            float v = zp[(size_t)(q * 128 + j) * HW];
            r[j] = __fmul_rn(v, v);
        }
        for (int i = 8; i < 128; i += 8) {
#pragma unroll
            for (int j = 0; j < 8; ++j) {
                float v = zp[(size_t)(q * 128 + i + j) * HW];
                r[j] = __fadd_rn(r[j], __fmul_rn(v, v));
            }
        }
        blk[q] = __fadd_rn(__fadd_rn(__fadd_rn(r[0], r[1]), __fadd_rn(r[2], r[3])),
                           __fadd_rn(__fadd_rn(r[4], r[5]), __fadd_rn(r[6], r[7])));
    }
    zz[n] = __fadd_rn(__fadd_rn(blk[0], blk[1]), __fadd_rn(blk[2], blk[3]));
}

// ---------------- K2: wsum = sum(m==0)
__global__ __launch_bounds__(256) void k_wsum(const float* __restrict__ m,
                                              double* __restrict__ accs) {
    __shared__ int sc[4];
    int tid = threadIdx.x;
    int base = blockIdx.x * 1024;
    int cnt = 0;
#pragma unroll
    for (int k2 = 0; k2 < 4; ++k2) cnt += (m[base + k2 * 256 + tid] == 0.0f) ? 1 : 0;
#pragma unroll
    for (int o = 32; o; o >>= 1) cnt += __shfl_xor(cnt, o);
    if ((tid & 63) == 0) sc[tid >> 6] = cnt;
    __syncthreads();
    if (tid == 0) atomicAdd(&accs[1], (double)(sc[0] + sc[1] + sc[2] + sc[3]));
}

// ---------------- K3: MFMA bf16 GEMM. Block 128m x 128n, 4 waves (2x2), wave 64x64.
// S~ = bf16(2z)·bf16(e). Per (row, nblock) store top-2 value + argmax index.
// BK=32 per LDS buffer (2 K-chunks), double-buffered: A 2x8KB @0, B 2x8KB @16384.
__global__ __launch_bounds__(256) void k_gemm(const float* __restrict__ z,
                                              const unsigned short* __restrict__ BT,
                                              float* __restrict__ bm1,
                                              float* __restrict__ bm2,
                                              int* __restrict__ bi1) {
    __shared__ char smem[32768];
    int tid = threadIdx.x;
    int l = tid & 63;
    int gq = tid >> 6;             // wave id = staging group (A mtile / B ntile)
    int wm = gq & 1, wn = gq >> 1;
    int nb = blockIdx.x & 63, mb = blockIdx.x >> 6;
    int khalf = l >> 5;

    // staging source pointers
    int m_glob = mb * 128 + gq * 32 + (l & 31);
    const float* zl = z + (size_t)(m_glob >> 12) * CCH * HW + (m_glob & 4095);

    f32x16 a00, a01, a10, a11;
#pragma unroll
    for (int i = 0; i < 16; ++i) { a00[i] = 0.f; a01[i] = 0.f; a10[i] = 0.f; a11[i] = 0.f; }

    short8 hv0, hv1;
    uint4 bv0, bv1;

// load K-chunks s2*2 and s2*2+1; convert A to bf16 immediately (keeps VGPR low)
#define LOADSTEP(S2) do { \
    int kb_ = (S2) * 32 + khalf * 8; \
    float av0_[8], av1_[8]; \
    _Pragma("unroll") for (int e = 0; e < 8; ++e) av0_[e] = zl[(size_t)(kb_ + e) * HW]; \
    _Pragma("unroll") for (int e = 0; e < 8; ++e) av1_[e] = zl[(size_t)(kb_ + 16 + e) * HW]; \
    size_t bgi_ = (((size_t)nb * 4 + gq) * 32 + (size_t)(S2) * 2) * 512 + (size_t)l * 8; \
    bv0 = *(const uint4*)&BT[bgi_]; \
    bv1 = *(const uint4*)&BT[bgi_ + 512]; \
    _Pragma("unroll") for (int e = 0; e < 8; ++e) { \
        hv0[e] = (short)(__float_as_uint(2.0f * av0_[e]) >> 16); \
        hv1[e] = (short)(__float_as_uint(2.0f * av1_[e]) >> 16); \
    } \
} while (0)

#define WRITESTEP(BUF) do { \
    int ab_ = (BUF) * 8192, bb_ = 16384 + (BUF) * 8192; \
    *(short8*)&smem[ab_ + 0 * 4096 + gq * 1024 + l * 16] = hv0; \
    *(short8*)&smem[ab_ + 1 * 4096 + gq * 1024 + l * 16] = hv1; \
    *(uint4*)&smem[bb_ + 0 * 4096 + gq * 1024 + l * 16] = bv0; \
    *(uint4*)&smem[bb_ + 1 * 4096 + gq * 1024 + l * 16] = bv1; \
} while (0)

    LOADSTEP(0);
    WRITESTEP(0);
    __syncthreads();

    for (int s2 = 0; s2 < 16; ++s2) {
        if (s2 < 15) LOADSTEP(s2 + 1);
        int ab = (s2 & 1) * 8192, bb = 16384 + (s2 & 1) * 8192;
#pragma unroll
        for (int sub = 0; sub < 2; ++sub) {
            short8 ah0 = *(short8*)&smem[ab + sub * 4096 + (wm * 2 + 0) * 1024 + l * 16];
            short8 ah1 = *(short8*)&smem[ab + sub * 4096 + (wm * 2 + 1) * 1024 + l * 16];
            short8 bh0 = *(short8*)&smem[bb + sub * 4096 + (wn * 2 + 0) * 1024 + l * 16];
            short8 bh1 = *(short8*)&smem[bb + sub * 4096 + (wn * 2 + 1) * 1024 + l * 16];
            a00 = __builtin_amdgcn_mfma_f32_32x32x16_bf16(ah0, bh0, a00, 0, 0, 0);
            a01 = __builtin_amdgcn_mfma_f32_32x32x16_bf16(ah0, bh1, a01, 0, 0, 0);
            a10 = __builtin_amdgcn_mfma_f32_32x32x16_bf16(ah1, bh0, a10, 0, 0, 0);
            a11 = __builtin_amdgcn_mfma_f32_32x32x16_bf16(ah1, bh1, a11, 0, 0, 0);
        }
        if (s2 < 15) {
            WRITESTEP((s2 + 1) & 1);
            __syncthreads();
        }
    }

    // Epilogue: per (row, this block's 128 j) top-2 + argmax.
    // D layout: col(j) = lane&31, row = (r&3) + 8*(r>>2) + 4*(lane>>5).
    float* ev1 = (float*)smem;            // [128 rows][2 wn]
    float* ev2 = (float*)(smem + 2048);
    int*   ei1 = (int*)(smem + 4096);
    int ja_base = nb * 128 + wn * 64 + (l & 31);
#pragma unroll
    for (int mtl = 0; mtl < 2; ++mtl) {
        const f32x16& t0 = mtl ? a10 : a00;
        const f32x16& t1 = mtl ? a11 : a01;
#pragma unroll
        for (int r = 0; r < 16; ++r) {
            float va = t0[r], vb = t1[r];
            int ja = ja_base, jb = ja_base + 32;
            float v1, v2; int i1;
            if (vb > va) { v1 = vb; i1 = jb; v2 = va; }
            else         { v1 = va; i1 = ja; v2 = vb; }
#pragma unroll
            for (int o = 1; o <= 16; o <<= 1) {
                float o1 = __shfl_xor(v1, o);
                float o2 = __shfl_xor(v2, o);
                int   oi = __shfl_xor(i1, o);
                if (o1 > v1) { v2 = fmaxf(v1, o2); v1 = o1; i1 = oi; }
                else         { v2 = fmaxf(v2, o1); }
            }
            if ((l & 31) == r) {
                int rl = wm * 64 + mtl * 32 + (r & 3) + 8 * (r >> 2) + 4 * khalf;
                ev1[rl * 2 + wn] = v1;
                ev2[rl * 2 + wn] = v2;
                ei1[rl * 2 + wn] = i1;
            }
        }
    }
    __syncthreads();
    if (tid < 128) {
        float p1 = ev1[tid * 2 + 0], p2 = ev2[tid * 2 + 0];
        int   pi = ei1[tid * 2 + 0];
        float q1 = ev1[tid * 2 + 1], q2 = ev2[tid * 2 + 1];
        int   qi = ei1[tid * 2 + 1];
        float v1, v2; int i1;
        if (q1 > p1) { v1 = q1; i1 = qi; v2 = fmaxf(p1, q2); }
        else         { v1 = p1; i1 = pi; v2 = fmaxf(q1, p2); }
        size_t rowg = (size_t)mb * 128 + tid;
        bm1[rowg * 64 + nb] = v1;
        bm2[rowg * 64 + nb] = v2;
        bi1[rowg * 64 + nb] = i1;
    }
}

// ---------------- K4: exact fp32-chain rescan of candidates; writes idx (bit-exact np argmin)
__global__ __launch_bounds__(64) void k_rescan(const float* __restrict__ z,
                                               const float* __restrict__ cb,
                                               const float* __restrict__ zz,
                                               const float* __restrict__ bm1,
                                               const float* __restrict__ bm2,
                                               const int* __restrict__ bi1,
                                               int* __restrict__ widx,
                                               float* __restrict__ out_idx) {
    __shared__ float a2[512];
    int row = blockIdx.x;
    int t = threadIdx.x;
    float v1 = bm1[(size_t)row * 64 + t];
    float v2 = bm2[(size_t)row * 64 + t];
    int   i1 = bi1[(size_t)row * 64 + t];
    float M = v1;
#pragma unroll
    for (int o = 1; o <= 32; o <<= 1) M = fmaxf(M, __shfl_xor(M, o));
    float th = M - THRESH;

    const float* zp = z + (size_t)(row >> 12) * CCH * HW + (row & 4095);
    for (int k = t; k < 512; k += 64) a2[k] = 2.0f * zp[(size_t)k * HW];
    float zzv = zz[row];
    __syncthreads();

    float bC = 3.0e38f;
    int bj = 0x7FFFFFFF;
    bool fullF = (v2 >= th);
    if (v1 >= th && !fullF) {
        const float* cr = cb + (size_t)i1 * CCH;
        float acc = 0.0f;
        for (int k = 0; k < 512; ++k) acc = __fmaf_rn(a2[k], cr[k], acc);
        bC = __fsub_rn(zzv, acc);
        bj = i1;
    }
    unsigned long long fm = __ballot(fullF);
    while (fm) {
        int nb2 = __ffsll(fm) - 1;
        fm &= fm - 1;
#pragma unroll
        for (int h = 0; h < 2; ++h) {
            int j = nb2 * 128 + h * 64 + t;
            const float* cr = cb + (size_t)j * CCH;
            float acc = 0.0f;
            for (int k = 0; k < 512; ++k) acc = __fmaf_rn(a2[k], cr[k], acc);
            float C = __fsub_rn(zzv, acc);
            if (C < bC || (C == bC && j < bj)) { bC = C; bj = j; }
        }
    }
#pragma unroll
    for (int o = 1; o <= 32; o <<= 1) {
        float oC = __shfl_xor(bC, o);
        int   oj = __shfl_xor(bj, o);
        if (oC < bC || (oC == bC && oj < bj)) { bC = oC; bj = oj; }
    }
    if (t == 0) { widx[row] = bj; out_idx[row] = (float)bj; }
}

// ---------------- K5: gather z_q, write z_q_st, accumulate loss numerator
__global__ __launch_bounds__(256) void k_out(const float* __restrict__ z,
                                             const float* __restrict__ cb,
                                             const float* __restrict__ m,
                                             const int* __restrict__ widx,
                                             float* __restrict__ out0,
                                             double* __restrict__ accs) {
    __shared__ float T[64 * 65];
    __shared__ float ls[4];
    int tid = threadIdx.x;
    int lhw = tid & 63, grp = tid >> 6;
    int bn = blockIdx.x >> 3, bc = blockIdx.x & 7;
    int n0 = bn * 64, c0 = bc * 64;
    int b = n0 >> 12, hw0 = n0 & 4095;
    const float* zb = z + (size_t)b * CCH * HW + hw0;
#pragma unroll
    for (int i = 0; i < 16; ++i) {
        int cl = grp + 4 * i;
        T[cl * 65 + lhw] = zb[(size_t)(c0 + cl) * HW + lhw];
    }
    __syncthreads();
    float la = 0.0f;
#pragma unroll
    for (int i = 0; i < 16; ++i) {
        int nl = grp + 4 * i;
        int n = n0 + nl;
        float zf = T[lhw * 65 + nl];
        int id = widx[n];
        float zq = cb[(size_t)id * CCH + c0 + lhw];
        float d = zq - zf;
        out0[(size_t)n * CCH + c0 + lhw] = zf + d;
        if (m[n] == 0.0f) la = fmaf(d, d, la);
    }
#pragma unroll
    for (int o = 32; o; o >>= 1) la += __shfl_xor(la, o);
    if ((tid & 63) == 0) ls[tid >> 6] = la;
    __syncthreads();
    if (tid == 0) atomicAdd(&accs[0], (double)(ls[0] + ls[1] + ls[2] + ls[3]));
}

// ---------------- K6: finalize loss = (1 + BETA) * mse
__global__ void k_final(const double* __restrict__ accs, float* __restrict__ outl) {
    double num = accs[0], wsum = accs[1];
    double denom = wsum * 512.0;
    double l1 = num / denom;
    outl[0] = (float)(l1 + 0.25 * l1);
}

extern "C" void kernel_launch(void* const* d_in, const int* in_sizes, int n_in,
                              void* d_out, int out_size, void* d_ws, size_t ws_size,
                              hipStream_t stream) {
    const float* z  = (const float*)d_in[0];
    const float* m  = (const float*)d_in[1];
    const float* cb = (const float*)d_in[2];
    float* out = (float*)d_out;
    char* ws = (char*)d_ws;

    unsigned short* BT   = (unsigned short*)(ws + WS_BT);
    float*  zzp  = (float*)(ws + WS_ZZ);
    float*  bm1  = (float*)(ws + WS_BM1);
    float*  bm2  = (float*)(ws + WS_BM2);
    int*    bi1  = (int*)(ws + WS_BI1);
    int*    widx = (int*)(ws + WS_IDX);
    double* accs = (double*)(ws + WS_ACC);

    float* out0    = out;
    float* outLoss = out + 16777216;
    float* outIdx  = out + 16777217;

    hipLaunchKernelGGL(k_prep_b, dim3(2048), dim3(256), 0, stream, cb, BT, accs);
    hipLaunchKernelGGL(k_zz,     dim3(128),  dim3(256), 0, stream, z, zzp);
    hipLaunchKernelGGL(k_wsum,   dim3(32),   dim3(256), 0, stream, m, accs);
    hipLaunchKernelGGL(k_gemm,   dim3(16384), dim3(256), 0, stream, z, BT, bm1, bm2, bi1);
    hipLaunchKernelGGL(k_rescan, dim3(32768), dim3(64), 0, stream, z, cb, zzp, bm1, bm2, bi1, widx, outIdx);
    hipLaunchKernelGGL(k_out,    dim3(4096), dim3(256), 0, stream, z, cb, m, widx, out0, accs);
    hipLaunchKernelGGL(k_final,  dim3(1),    dim3(1),   0, stream, accs, outLoss);
}

// Round 3
// 1027.078 us; speedup vs baseline: 1.3844x; 1.1563x over previous
//
#include <hip/hip_runtime.h>
#include <math.h>

#define CCH 512
#define HW 4096
#define NN 32768
#define NE 8192

// ws layout (bytes)
#define WS_BT  0                         // BT bf16 fragment-order: 8192*512*2B = 8388608
#define WS_ZZ  (8388608)                 // zz f32 [32768]
#define WS_BM1 (WS_ZZ + 131072)          // blockmax v1 [32768][64] f32 = 8388608
#define WS_BM2 (WS_BM1 + 8388608)        // blockmax v2 [32768][64] f32
#define WS_BI1 (WS_BM2 + 8388608)        // blockmax i1 [32768][64] i32
#define WS_IDX (WS_BI1 + 8388608)        // final idx [32768] i32
#define WS_ACC (WS_IDX + 131072)         // accs[0]=loss num, accs[1]=wsum (f64)
// AT (bf16(2z) fragment-order, 32768*512*2B = 33.5MB) lives in d_out[0..8388608 floats):
// written by k_prep_a, last read by k_gemm, then overwritten by k_out. Sequential stream => safe.

// bf16-only GEMM: score error std ~2.7e-5; THRESH = 1e-3 >> 30 sigma guard.
#define THRESH 1.0e-3f

typedef __attribute__((ext_vector_type(8)))  short short8;   // 8 bf16 (4 VGPRs)
typedef __attribute__((ext_vector_type(16))) float f32x16;   // 32x32 MFMA acc

__device__ __forceinline__ void gll16(const void* g, void* l) {
    __builtin_amdgcn_global_load_lds((const __attribute__((address_space(1))) void*)g,
                                     (__attribute__((address_space(3))) void*)l, 16, 0, 0);
}

// ---------------- K0: cb -> BT bf16, fragment-linear layout; zero accs
// chunk(jt32, s): 64 lanes x 16B; lane l holds cb[j=jt*32+(l&31)][k=s*16+(l>>5)*8 + e], e=0..7
__global__ __launch_bounds__(256) void k_prep_b(const float* __restrict__ cb,
                                                unsigned short* __restrict__ BT,
                                                double* __restrict__ accs) {
    int t = blockIdx.x * 256 + threadIdx.x;
    if (t == 0) { accs[0] = 0.0; accs[1] = 0.0; }
    int l = t & 63, s = (t >> 6) & 31, jt = t >> 11;
    int j = jt * 32 + (l & 31);
    int kb = s * 16 + (l >> 5) * 8;
    short8 hv;
#pragma unroll
    for (int e = 0; e < 8; ++e) {
        float x = cb[(size_t)j * CCH + kb + e];
        hv[e] = (short)(__float_as_uint(x) >> 16);   // truncation to bf16
    }
    size_t chunk = (size_t)jt * 32 + s;
    *(short8*)&BT[chunk * 512 + (size_t)l * 8] = hv;
}

// ---------------- K0b: z -> AT = bf16(2z), same fragment-linear chunk layout as BT.
// chunk = mt*32+s; lane l holds 2z[m=mt*32+(l&31)][k=s*16+(l>>5)*8+e]
__global__ __launch_bounds__(256) void k_prep_a(const float* __restrict__ z,
                                                unsigned short* __restrict__ AT) {
    int t = blockIdx.x * 256 + threadIdx.x;
    int l = t & 63;
    int chunk = t >> 6;                  // [0, 32768)
    int mt = chunk >> 5, s = chunk & 31;
    int m = mt * 32 + (l & 31);
    int kb = s * 16 + (l >> 5) * 8;
    const float* zp = z + (size_t)(m >> 12) * CCH * HW + (m & 4095);
    short8 hv;
#pragma unroll
    for (int e = 0; e < 8; ++e) {
        float x = 2.0f * zp[(size_t)(kb + e) * HW];      // *2 exact (pow2)
        hv[e] = (short)(__float_as_uint(x) >> 16);       // truncation to bf16
    }
    *(short8*)&AT[(size_t)chunk * 512 + (size_t)l * 8] = hv;
}

// ---------------- K1: zz[n] = np.sum(zf*zf, axis=1), numpy's exact pairwise tree
__global__ __launch_bounds__(256) void k_zz(const float* __restrict__ z,
                                            float* __restrict__ zz) {
    int t = threadIdx.x;
    int n = blockIdx.x * 256 + t;
    int b = n >> 12, hw = n & 4095;
    const float* zp = z + (size_t)b * CCH * HW + hw;
    float blk[4];
#pragma unroll
    for (int q = 0; q < 4; ++q) {
        float r[8];
#pragma unroll
        for (int j = 0; j < 8; ++j) {
            float v = zp[(size_t)(q * 128 + j) * HW];
            r[j] = __fmul_rn(v, v);
        }
        for (int i = 8; i < 128; i += 8) {
#pragma unroll
            for (int j = 0; j < 8; ++j) {
                float v = zp[(size_t)(q * 128 + i + j) * HW];
                r[j] = __fadd_rn(r[j], __fmul_rn(v, v));
            }
        }
        blk[q] = __fadd_rn(__fadd_rn(__fadd_rn(r[0], r[1]), __fadd_rn(r[2], r[3])),
                           __fadd_rn(__fadd_rn(r[4], r[5]), __fadd_rn(r[6], r[7])));
    }
    zz[n] = __fadd_rn(__fadd_rn(blk[0], blk[1]), __fadd_rn(blk[2], blk[3]));
}

// ---------------- K2: wsum = sum(m==0)
__global__ __launch_bounds__(256) void k_wsum(const float* __restrict__ m,
                                              double* __restrict__ accs) {
    __shared__ int sc[4];
    int tid = threadIdx.x;
    int base = blockIdx.x * 1024;
    int cnt = 0;
#pragma unroll
    for (int k2 = 0; k2 < 4; ++k2) cnt += (m[base + k2 * 256 + tid] == 0.0f) ? 1 : 0;
#pragma unroll
    for (int o = 32; o; o >>= 1) cnt += __shfl_xor(cnt, o);
    if ((tid & 63) == 0) sc[tid >> 6] = cnt;
    __syncthreads();
    if (tid == 0) atomicAdd(&accs[1], (double)(sc[0] + sc[1] + sc[2] + sc[3]));
}

// ---------------- K3: pre-packed bf16 MFMA GEMM. Block 128m x 256n, 4 waves (2x2),
// wave tile 64x128 (2x4 frags of 32x32). Staging via global_load_lds w16, 2-phase dbuf.
// LDS: A 2buf x 4mt x 2kc x 1KB = 16KB @0 ; B 2buf x 8nt x 2kc x 1KB = 32KB @16384.
__global__ __launch_bounds__(256, 2) void k_gemm(const unsigned short* __restrict__ AT,
                                                 const unsigned short* __restrict__ BT,
                                                 float* __restrict__ bm1,
                                                 float* __restrict__ bm2,
                                                 int* __restrict__ bi1) {
    __shared__ char smem[49152];
    int tid = threadIdx.x;
    int l = tid & 63;
    int gq = tid >> 6;             // wave id
    int wm = gq & 1, wn = gq >> 1; // 2x2 wave grid
    int nb = blockIdx.x & 31, mb = blockIdx.x >> 5;
    int khalf = l >> 5;

    // staging sources: wave gq stages A-tile mt=gq and B-tiles nt=2gq,2gq+1
    const char* aSrc  = (const char*)AT + (size_t)(mb * 4 + gq) * 32768 + (size_t)l * 16;
    const char* bSrc0 = (const char*)BT + (size_t)(nb * 8 + 2 * gq) * 32768 + (size_t)l * 16;
    const char* bSrc1 = bSrc0 + 32768;

    f32x16 acc[2][4];
#pragma unroll
    for (int m = 0; m < 2; ++m)
#pragma unroll
        for (int n = 0; n < 4; ++n)
#pragma unroll
            for (int i = 0; i < 16; ++i) acc[m][n][i] = 0.f;

#define STAGE(S2, BUF) do { \
    size_t so_ = (size_t)(S2) * 2048; \
    char* ab_ = smem + (BUF) * 8192 + gq * 2048; \
    char* bb_ = smem + 16384 + (BUF) * 16384 + gq * 4096; \
    gll16(aSrc + so_,         ab_); \
    gll16(aSrc + so_ + 1024,  ab_ + 1024); \
    gll16(bSrc0 + so_,        bb_); \
    gll16(bSrc0 + so_ + 1024, bb_ + 1024); \
    gll16(bSrc1 + so_,        bb_ + 2048); \
    gll16(bSrc1 + so_ + 1024, bb_ + 3072); \
} while (0)

    STAGE(0, 0);
    __syncthreads();

    for (int s2 = 0; s2 < 16; ++s2) {
        int buf = s2 & 1;
        if (s2 < 15) STAGE(s2 + 1, buf ^ 1);
        const char* ab = smem + buf * 8192;
        const char* bb = smem + 16384 + buf * 16384;
#pragma unroll
        for (int kc = 0; kc < 2; ++kc) {
            short8 a0 = *(const short8*)(ab + ((wm * 2 + 0) * 2 + kc) * 1024 + l * 16);
            short8 a1 = *(const short8*)(ab + ((wm * 2 + 1) * 2 + kc) * 1024 + l * 16);
            short8 b0 = *(const short8*)(bb + ((wn * 4 + 0) * 2 + kc) * 1024 + l * 16);
            short8 b1 = *(const short8*)(bb + ((wn * 4 + 1) * 2 + kc) * 1024 + l * 16);
            short8 b2 = *(const short8*)(bb + ((wn * 4 + 2) * 2 + kc) * 1024 + l * 16);
            short8 b3 = *(const short8*)(bb + ((wn * 4 + 3) * 2 + kc) * 1024 + l * 16);
            acc[0][0] = __builtin_amdgcn_mfma_f32_32x32x16_bf16(a0, b0, acc[0][0], 0, 0, 0);
            acc[0][1] = __builtin_amdgcn_mfma_f32_32x32x16_bf16(a0, b1, acc[0][1], 0, 0, 0);
            acc[0][2] = __builtin_amdgcn_mfma_f32_32x32x16_bf16(a0, b2, acc[0][2], 0, 0, 0);
            acc[0][3] = __builtin_amdgcn_mfma_f32_32x32x16_bf16(a0, b3, acc[0][3], 0, 0, 0);
            acc[1][0] = __builtin_amdgcn_mfma_f32_32x32x16_bf16(a1, b0, acc[1][0], 0, 0, 0);
            acc[1][1] = __builtin_amdgcn_mfma_f32_32x32x16_bf16(a1, b1, acc[1][1], 0, 0, 0);
            acc[1][2] = __builtin_amdgcn_mfma_f32_32x32x16_bf16(a1, b2, acc[1][2], 0, 0, 0);
            acc[1][3] = __builtin_amdgcn_mfma_f32_32x32x16_bf16(a1, b3, acc[1][3], 0, 0, 0);
        }
        if (s2 < 15) __syncthreads();
    }

    // Epilogue: wave owns a full 128-col half (hb = nb*2+wn). Per row: top-2 + argmax,
    // wave-local (4 frags + 32-lane shuffle reduce), direct global write.
    // D layout: col(j)=lane&31, row=(r&3)+8*(r>>2)+4*(lane>>5).
    int colb = nb * 256 + wn * 128 + (l & 31);
#pragma unroll
    for (int m = 0; m < 2; ++m) {
#pragma unroll
        for (int r = 0; r < 16; ++r) {
            float v0 = acc[m][0][r], v1f = acc[m][1][r];
            float v2f = acc[m][2][r], v3f = acc[m][3][r];
            float p1, p2; int pi;
            if (v1f > v0)  { p1 = v1f; pi = 1; p2 = v0; }  else { p1 = v0;  pi = 0; p2 = v1f; }
            float q1, q2; int qi;
            if (v3f > v2f) { q1 = v3f; qi = 3; q2 = v2f; } else { q1 = v2f; qi = 2; q2 = v3f; }
            float w1, w2; int wi;
            if (q1 > p1) { w1 = q1; wi = qi; w2 = fmaxf(p1, q2); }
            else         { w1 = p1; wi = pi; w2 = fmaxf(q1, p2); }
            int ci = colb + wi * 32;
#pragma unroll
            for (int o = 1; o <= 16; o <<= 1) {
                float o1 = __shfl_xor(w1, o);
                float o2 = __shfl_xor(w2, o);
                int   oi = __shfl_xor(ci, o);
                if (o1 > w1) { w2 = fmaxf(w1, o2); w1 = o1; ci = oi; }
                else         { w2 = fmaxf(w2, o1); }
            }
            if ((l & 31) == r) {
                int rl = wm * 64 + m * 32 + (r & 3) + 8 * (r >> 2) + 4 * khalf;
                size_t rowg = (size_t)mb * 128 + rl;
                int hb = nb * 2 + wn;
                bm1[rowg * 64 + hb] = w1;
                bm2[rowg * 64 + hb] = w2;
                bi1[rowg * 64 + hb] = ci;
            }
        }
    }
}

// ---------------- K4: exact fp32-chain rescan of candidates; writes idx (bit-exact np argmin)
__global__ __launch_bounds__(64) void k_rescan(const float* __restrict__ z,
                                               const float* __restrict__ cb,
                                               const float* __restrict__ zz,
                                               const float* __restrict__ bm1,
                                               const float* __restrict__ bm2,
                                               const int* __restrict__ bi1,
                                               int* __restrict__ widx,
                                               float* __restrict__ out_idx) {
    __shared__ float a2[512];
    int row = blockIdx.x;
    int t = threadIdx.x;
    float v1 = bm1[(size_t)row * 64 + t];
    float v2 = bm2[(size_t)row * 64 + t];
    int   i1 = bi1[(size_t)row * 64 + t];
    float M = v1;
#pragma unroll
    for (int o = 1; o <= 32; o <<= 1) M = fmaxf(M, __shfl_xor(M, o));
    float th = M - THRESH;

    const float* zp = z + (size_t)(row >> 12) * CCH * HW + (row & 4095);
    for (int k = t; k < 512; k += 64) a2[k] = 2.0f * zp[(size_t)k * HW];
    float zzv = zz[row];
    __syncthreads();

    float bC = 3.0e38f;
    int bj = 0x7FFFFFFF;
    bool fullF = (v2 >= th);
    if (v1 >= th && !fullF) {
        const float* cr = cb + (size_t)i1 * CCH;
        float acc = 0.0f;
        for (int k = 0; k < 512; ++k) acc = __fmaf_rn(a2[k], cr[k], acc);
        bC = __fsub_rn(zzv, acc);
        bj = i1;
    }
    unsigned long long fm = __ballot(fullF);
    while (fm) {
        int nb2 = __ffsll(fm) - 1;
        fm &= fm - 1;
#pragma unroll
        for (int h = 0; h < 2; ++h) {
            int j = nb2 * 128 + h * 64 + t;
            const float* cr = cb + (size_t)j * CCH;
            float acc = 0.0f;
            for (int k = 0; k < 512; ++k) acc = __fmaf_rn(a2[k], cr[k], acc);
            float C = __fsub_rn(zzv, acc);
            if (C < bC || (C == bC && j < bj)) { bC = C; bj = j; }
        }
    }
#pragma unroll
    for (int o = 1; o <= 32; o <<= 1) {
        float oC = __shfl_xor(bC, o);
        int   oj = __shfl_xor(bj, o);
        if (oC < bC || (oC == bC && oj < bj)) { bC = oC; bj = oj; }
    }
    if (t == 0) { widx[row] = bj; out_idx[row] = (float)bj; }
}

// ---------------- K5: gather z_q, write z_q_st, accumulate loss numerator
__global__ __launch_bounds__(256) void k_out(const float* __restrict__ z,
                                             const float* __restrict__ cb,
                                             const float* __restrict__ m,
                                             const int* __restrict__ widx,
                                             float* __restrict__ out0,
                                             double* __restrict__ accs) {
    __shared__ float T[64 * 65];
    __shared__ float ls[4];
    int tid = threadIdx.x;
    int lhw = tid & 63, grp = tid >> 6;
    int bn = blockIdx.x >> 3, bc = blockIdx.x & 7;
    int n0 = bn * 64, c0 = bc * 64;
    int b = n0 >> 12, hw0 = n0 & 4095;
    const float* zb = z + (size_t)b * CCH * HW + hw0;
#pragma unroll
    for (int i = 0; i < 16; ++i) {
        int cl = grp + 4 * i;
        T[cl * 65 + lhw] = zb[(size_t)(c0 + cl) * HW + lhw];
    }
    __syncthreads();
    float la = 0.0f;
#pragma unroll
    for (int i = 0; i < 16; ++i) {
        int nl = grp + 4 * i;
        int n = n0 + nl;
        float zf = T[lhw * 65 + nl];
        int id = widx[n];
        float zq = cb[(size_t)id * CCH + c0 + lhw];
        float d = zq - zf;
        out0[(size_t)n * CCH + c0 + lhw] = zf + d;
        if (m[n] == 0.0f) la = fmaf(d, d, la);
    }
#pragma unroll
    for (int o = 32; o; o >>= 1) la += __shfl_xor(la, o);
    if ((tid & 63) == 0) ls[tid >> 6] = la;
    __syncthreads();
    if (tid == 0) atomicAdd(&accs[0], (double)(ls[0] + ls[1] + ls[2] + ls[3]));
}

// ---------------- K6: finalize loss = (1 + BETA) * mse
__global__ void k_final(const double* __restrict__ accs, float* __restrict__ outl) {
    double num = accs[0], wsum = accs[1];
    double denom = wsum * 512.0;
    double l1 = num / denom;
    outl[0] = (float)(l1 + 0.25 * l1);
}

extern "C" void kernel_launch(void* const* d_in, const int* in_sizes, int n_in,
                              void* d_out, int out_size, void* d_ws, size_t ws_size,
                              hipStream_t stream) {
    const float* z  = (const float*)d_in[0];
    const float* m  = (const float*)d_in[1];
    const float* cb = (const float*)d_in[2];
    float* out = (float*)d_out;
    char* ws = (char*)d_ws;

    unsigned short* BT   = (unsigned short*)(ws + WS_BT);
    float*  zzp  = (float*)(ws + WS_ZZ);
    float*  bm1  = (float*)(ws + WS_BM1);
    float*  bm2  = (float*)(ws + WS_BM2);
    int*    bi1  = (int*)(ws + WS_BI1);
    int*    widx = (int*)(ws + WS_IDX);
    double* accs = (double*)(ws + WS_ACC);

    float* out0    = out;
    float* outLoss = out + 16777216;
    float* outIdx  = out + 16777217;

    // AT scratch lives in the first 33.5MB of d_out (overwritten later by k_out).
    unsigned short* AT = (unsigned short*)out;

    hipLaunchKernelGGL(k_prep_b, dim3(2048), dim3(256), 0, stream, cb, BT, accs);
    hipLaunchKernelGGL(k_prep_a, dim3(8192), dim3(256), 0, stream, z, AT);
    hipLaunchKernelGGL(k_zz,     dim3(128),  dim3(256), 0, stream, z, zzp);
    hipLaunchKernelGGL(k_wsum,   dim3(32),   dim3(256), 0, stream, m, accs);
    hipLaunchKernelGGL(k_gemm,   dim3(8192), dim3(256), 0, stream, AT, BT, bm1, bm2, bi1);
    hipLaunchKernelGGL(k_rescan, dim3(32768), dim3(64), 0, stream, z, cb, zzp, bm1, bm2, bi1, widx, outIdx);
    hipLaunchKernelGGL(k_out,    dim3(4096), dim3(256), 0, stream, z, cb, m, widx, out0, accs);
    hipLaunchKernelGGL(k_final,  dim3(1),    dim3(1),   0, stream, accs, outLoss);
}

// Round 4
// 981.166 us; speedup vs baseline: 1.4492x; 1.0468x over previous
//
#include <hip/hip_runtime.h>
#include <math.h>

#define CCH 512
#define HW 4096
#define NN 32768
#define NE 8192

// ws layout (bytes)
#define WS_BT  0                         // BT bf16 fragment-order: 8192*512*2B = 8388608
#define WS_ZZ  (8388608)                 // zz f32 [32768]
#define WS_BM1 (WS_ZZ + 131072)          // blockmax v1 [32768][64] f32 = 8388608
#define WS_BM2 (WS_BM1 + 8388608)        // blockmax v2 [32768][64] f32
#define WS_BI1 (WS_BM2 + 8388608)        // blockmax i1 [32768][64] i32
#define WS_IDX (WS_BI1 + 8388608)        // final idx [32768] i32
#define WS_ACC (WS_IDX + 131072)         // accs[0]=loss num, accs[1]=wsum (f64)
// AT (bf16(2z) fragment-order, 32768*512*2B = 33.5MB) lives in d_out[0..8388608 floats):
// written by k_prep_a, last read by k_gemm, then overwritten by k_out. Sequential stream => safe.

// bf16-only GEMM: score error std ~2.7e-5; THRESH = 1e-3 >> 30 sigma guard.
#define THRESH 1.0e-3f

typedef __attribute__((ext_vector_type(8)))  short short8;   // 8 bf16 (4 VGPRs)
typedef __attribute__((ext_vector_type(16))) float f32x16;   // 32x32 MFMA acc

__device__ __forceinline__ void gll16(const void* g, void* l) {
    __builtin_amdgcn_global_load_lds((const __attribute__((address_space(1))) void*)g,
                                     (__attribute__((address_space(3))) void*)l, 16, 0, 0);
}

// ---------------- K0: cb -> BT bf16, fragment-linear layout; zero accs
// chunk(jt32, s): 64 lanes x 16B; lane l holds cb[j=jt*32+(l&31)][k=s*16+(l>>5)*8 + e], e=0..7
__global__ __launch_bounds__(256) void k_prep_b(const float* __restrict__ cb,
                                                unsigned short* __restrict__ BT,
                                                double* __restrict__ accs) {
    int t = blockIdx.x * 256 + threadIdx.x;
    if (t == 0) { accs[0] = 0.0; accs[1] = 0.0; }
    int l = t & 63, s = (t >> 6) & 31, jt = t >> 11;
    int j = jt * 32 + (l & 31);
    int kb = s * 16 + (l >> 5) * 8;
    short8 hv;
#pragma unroll
    for (int e = 0; e < 8; ++e) {
        float x = cb[(size_t)j * CCH + kb + e];
        hv[e] = (short)(__float_as_uint(x) >> 16);   // truncation to bf16
    }
    size_t chunk = (size_t)jt * 32 + s;
    *(short8*)&BT[chunk * 512 + (size_t)l * 8] = hv;
}

// ---------------- K0b: z -> AT = bf16(2z), same fragment-linear chunk layout as BT.
// chunk = mt*32+s; lane l holds 2z[m=mt*32+(l&31)][k=s*16+(l>>5)*8+e]
__global__ __launch_bounds__(256) void k_prep_a(const float* __restrict__ z,
                                                unsigned short* __restrict__ AT) {
    int t = blockIdx.x * 256 + threadIdx.x;
    int l = t & 63;
    int chunk = t >> 6;                  // [0, 32768)
    int mt = chunk >> 5, s = chunk & 31;
    int m = mt * 32 + (l & 31);
    int kb = s * 16 + (l >> 5) * 8;
    const float* zp = z + (size_t)(m >> 12) * CCH * HW + (m & 4095);
    short8 hv;
#pragma unroll
    for (int e = 0; e < 8; ++e) {
        float x = 2.0f * zp[(size_t)(kb + e) * HW];      // *2 exact (pow2)
        hv[e] = (short)(__float_as_uint(x) >> 16);       // truncation to bf16
    }
    *(short8*)&AT[(size_t)chunk * 512 + (size_t)l * 8] = hv;
}

// ---------------- K1: zz[n] = np.sum(zf*zf, axis=1), numpy's exact pairwise tree
__global__ __launch_bounds__(256) void k_zz(const float* __restrict__ z,
                                            float* __restrict__ zz) {
    int t = threadIdx.x;
    int n = blockIdx.x * 256 + t;
    int b = n >> 12, hw = n & 4095;
    const float* zp = z + (size_t)b * CCH * HW + hw;
    float blk[4];
#pragma unroll
    for (int q = 0; q < 4; ++q) {
        float r[8];
#pragma unroll
        for (int j = 0; j < 8; ++j) {
            float v = zp[(size_t)(q * 128 + j) * HW];
            r[j] = __fmul_rn(v, v);
        }
        for (int i = 8; i < 128; i += 8) {
#pragma unroll
            for (int j = 0; j < 8; ++j) {
                float v = zp[(size_t)(q * 128 + i + j) * HW];
                r[j] = __fadd_rn(r[j], __fmul_rn(v, v));
            }
        }
        blk[q] = __fadd_rn(__fadd_rn(__fadd_rn(r[0], r[1]), __fadd_rn(r[2], r[3])),
                           __fadd_rn(__fadd_rn(r[4], r[5]), __fadd_rn(r[6], r[7])));
    }
    zz[n] = __fadd_rn(__fadd_rn(blk[0], blk[1]), __fadd_rn(blk[2], blk[3]));
}

// ---------------- K2: wsum = sum(m==0)
__global__ __launch_bounds__(256) void k_wsum(const float* __restrict__ m,
                                              double* __restrict__ accs) {
    __shared__ int sc[4];
    int tid = threadIdx.x;
    int base = blockIdx.x * 1024;
    int cnt = 0;
#pragma unroll
    for (int k2 = 0; k2 < 4; ++k2) cnt += (m[base + k2 * 256 + tid] == 0.0f) ? 1 : 0;
#pragma unroll
    for (int o = 32; o; o >>= 1) cnt += __shfl_xor(cnt, o);
    if ((tid & 63) == 0) sc[tid >> 6] = cnt;
    __syncthreads();
    if (tid == 0) atomicAdd(&accs[1], (double)(sc[0] + sc[1] + sc[2] + sc[3]));
}

// ---------------- K3: pre-packed bf16 MFMA GEMM, counted-vmcnt 4-ring pipeline (T3+T4).
// Block 128m x 256n, 4 waves (2x2), wave tile 64x128 (2x4 frags of 32x32), BK=16/tile.
// LDS ring: A 4 x 4KB @0 ; B 4 x 8KB @16384 = 49152 B total -> 3 blocks/CU.
// Per tile per wave: 3 global_load_lds (1 A + 2 B), 6 ds_read_b128, 8 MFMA.
// Protocol: vmcnt(6) keeps 2 tiles (6 loads) in flight across every barrier; never drains.
__global__ __launch_bounds__(256, 3) void k_gemm(const unsigned short* __restrict__ AT,
                                                 const unsigned short* __restrict__ BT,
                                                 float* __restrict__ bm1,
                                                 float* __restrict__ bm2,
                                                 int* __restrict__ bi1) {
    __shared__ char smem[49152];
    int tid = threadIdx.x;
    int l = tid & 63;
    int gq = tid >> 6;             // wave id
    int wm = gq & 1, wn = gq >> 1; // 2x2 wave grid
    int nb = blockIdx.x & 31, mb = blockIdx.x >> 5;
    int khalf = l >> 5;

    // staging sources: wave gq stages A-chunk mt=gq and B-chunks nt=2gq,2gq+1
    const char* aSrc  = (const char*)AT + (size_t)(mb * 4 + gq) * 32768 + (size_t)l * 16;
    const char* bSrc0 = (const char*)BT + (size_t)(nb * 8 + 2 * gq) * 32768 + (size_t)l * 16;
    const char* bSrc1 = bSrc0 + 32768;

    f32x16 acc[2][4];
#pragma unroll
    for (int m = 0; m < 2; ++m)
#pragma unroll
        for (int n = 0; n < 4; ++n)
#pragma unroll
            for (int i = 0; i < 16; ++i) acc[m][n][i] = 0.f;

// stage tile T into ring slot BUF (3 gll16 per wave; LDS dest wave-uniform base)
#define STAGE(T, BUF) do { \
    size_t so_ = (size_t)(T) * 1024; \
    gll16(aSrc + so_,  smem + (BUF) * 4096 + gq * 1024); \
    gll16(bSrc0 + so_, smem + 16384 + (BUF) * 8192 + (2 * gq + 0) * 1024); \
    gll16(bSrc1 + so_, smem + 16384 + (BUF) * 8192 + (2 * gq + 1) * 1024); \
} while (0)

// pipeline sync: certify my oldest tile landed (counted vmcnt), publish via barrier.
// sched_barrier(0) pins: nothing crosses up past the waitcnt, nothing crosses down past barrier.
#define PIPE_SYNC(NSTR) do { \
    __builtin_amdgcn_sched_barrier(0); \
    asm volatile("s_waitcnt vmcnt(" NSTR ")" ::: "memory"); \
    __builtin_amdgcn_s_barrier(); \
    __builtin_amdgcn_sched_barrier(0); \
} while (0)

// compute tile in ring slot CUR: 6 ds_read_b128 -> 8 MFMA (setprio-wrapped)
#define COMPUTE(CUR) do { \
    const char* ab_ = smem + (CUR) * 4096; \
    const char* bb_ = smem + 16384 + (CUR) * 8192; \
    short8 a0 = *(const short8*)(ab_ + (wm * 2 + 0) * 1024 + l * 16); \
    short8 a1 = *(const short8*)(ab_ + (wm * 2 + 1) * 1024 + l * 16); \
    short8 b0 = *(const short8*)(bb_ + (wn * 4 + 0) * 1024 + l * 16); \
    short8 b1 = *(const short8*)(bb_ + (wn * 4 + 1) * 1024 + l * 16); \
    short8 b2 = *(const short8*)(bb_ + (wn * 4 + 2) * 1024 + l * 16); \
    short8 b3 = *(const short8*)(bb_ + (wn * 4 + 3) * 1024 + l * 16); \
    __builtin_amdgcn_s_setprio(1); \
    acc[0][0] = __builtin_amdgcn_mfma_f32_32x32x16_bf16(a0, b0, acc[0][0], 0, 0, 0); \
    acc[0][1] = __builtin_amdgcn_mfma_f32_32x32x16_bf16(a0, b1, acc[0][1], 0, 0, 0); \
    acc[0][2] = __builtin_amdgcn_mfma_f32_32x32x16_bf16(a0, b2, acc[0][2], 0, 0, 0); \
    acc[0][3] = __builtin_amdgcn_mfma_f32_32x32x16_bf16(a0, b3, acc[0][3], 0, 0, 0); \
    acc[1][0] = __builtin_amdgcn_mfma_f32_32x32x16_bf16(a1, b0, acc[1][0], 0, 0, 0); \
    acc[1][1] = __builtin_amdgcn_mfma_f32_32x32x16_bf16(a1, b1, acc[1][1], 0, 0, 0); \
    acc[1][2] = __builtin_amdgcn_mfma_f32_32x32x16_bf16(a1, b2, acc[1][2], 0, 0, 0); \
    acc[1][3] = __builtin_amdgcn_mfma_f32_32x32x16_bf16(a1, b3, acc[1][3], 0, 0, 0); \
    __builtin_amdgcn_s_setprio(0); \
} while (0)

    // prologue: 3 tiles in flight (9 loads/wave)
    STAGE(0, 0);
    STAGE(1, 1);
    STAGE(2, 2);

    // main: tiles 0..28 with full prefetch; vmcnt(6) = 2 tiles may remain in flight
    for (int s = 0; s < 29; ++s) {
        PIPE_SYNC("6");
        STAGE(s + 3, (s + 3) & 3);
        COMPUTE(s & 3);
    }
    // tails: tiles 29,30,31 (outstanding 9 -> 6 -> 3 -> 0)
    PIPE_SYNC("6");
    COMPUTE(1);            // tile 29, slot 29&3=1
    PIPE_SYNC("3");
    COMPUTE(2);            // tile 30
    PIPE_SYNC("0");
    COMPUTE(3);            // tile 31

    // Epilogue: wave owns a full 128-col half (hb = nb*2+wn). Per row: top-2 + argmax,
    // wave-local (4 frags + 32-lane shuffle reduce), direct global write.
    // D layout: col(j)=lane&31, row=(r&3)+8*(r>>2)+4*(lane>>5).
    int colb = nb * 256 + wn * 128 + (l & 31);
#pragma unroll
    for (int m = 0; m < 2; ++m) {
#pragma unroll
        for (int r = 0; r < 16; ++r) {
            float v0 = acc[m][0][r], v1f = acc[m][1][r];
            float v2f = acc[m][2][r], v3f = acc[m][3][r];
            float p1, p2; int pi;
            if (v1f > v0)  { p1 = v1f; pi = 1; p2 = v0; }  else { p1 = v0;  pi = 0; p2 = v1f; }
            float q1, q2; int qi;
            if (v3f > v2f) { q1 = v3f; qi = 3; q2 = v2f; } else { q1 = v2f; qi = 2; q2 = v3f; }
            float w1, w2; int wi;
            if (q1 > p1) { w1 = q1; wi = qi; w2 = fmaxf(p1, q2); }
            else         { w1 = p1; wi = pi; w2 = fmaxf(q1, p2); }
            int ci = colb + wi * 32;
#pragma unroll
            for (int o = 1; o <= 16; o <<= 1) {
                float o1 = __shfl_xor(w1, o);
                float o2 = __shfl_xor(w2, o);
                int   oi = __shfl_xor(ci, o);
                if (o1 > w1) { w2 = fmaxf(w1, o2); w1 = o1; ci = oi; }
                else         { w2 = fmaxf(w2, o1); }
            }
            if ((l & 31) == r) {
                int rl = wm * 64 + m * 32 + (r & 3) + 8 * (r >> 2) + 4 * khalf;
                size_t rowg = (size_t)mb * 128 + rl;
                int hb = nb * 2 + wn;
                bm1[rowg * 64 + hb] = w1;
                bm2[rowg * 64 + hb] = w2;
                bi1[rowg * 64 + hb] = ci;
            }
        }
    }
}

// ---------------- K4: exact fp32-chain rescan of candidates; writes idx (bit-exact np argmin)
__global__ __launch_bounds__(64) void k_rescan(const float* __restrict__ z,
                                               const float* __restrict__ cb,
                                               const float* __restrict__ zz,
                                               const float* __restrict__ bm1,
                                               const float* __restrict__ bm2,
                                               const int* __restrict__ bi1,
                                               int* __restrict__ widx,
                                               float* __restrict__ out_idx) {
    __shared__ float a2[512];
    int row = blockIdx.x;
    int t = threadIdx.x;
    float v1 = bm1[(size_t)row * 64 + t];
    float v2 = bm2[(size_t)row * 64 + t];
    int   i1 = bi1[(size_t)row * 64 + t];
    float M = v1;
#pragma unroll
    for (int o = 1; o <= 32; o <<= 1) M = fmaxf(M, __shfl_xor(M, o));
    float th = M - THRESH;

    const float* zp = z + (size_t)(row >> 12) * CCH * HW + (row & 4095);
    for (int k = t; k < 512; k += 64) a2[k] = 2.0f * zp[(size_t)k * HW];
    float zzv = zz[row];
    __syncthreads();

    float bC = 3.0e38f;
    int bj = 0x7FFFFFFF;
    bool fullF = (v2 >= th);
    if (v1 >= th && !fullF) {
        const float* cr = cb + (size_t)i1 * CCH;
        float acc = 0.0f;
        for (int k = 0; k < 512; ++k) acc = __fmaf_rn(a2[k], cr[k], acc);
        bC = __fsub_rn(zzv, acc);
        bj = i1;
    }
    unsigned long long fm = __ballot(fullF);
    while (fm) {
        int nb2 = __ffsll(fm) - 1;
        fm &= fm - 1;
#pragma unroll
        for (int h = 0; h < 2; ++h) {
            int j = nb2 * 128 + h * 64 + t;
            const float* cr = cb + (size_t)j * CCH;
            float acc = 0.0f;
            for (int k = 0; k < 512; ++k) acc = __fmaf_rn(a2[k], cr[k], acc);
            float C = __fsub_rn(zzv, acc);
            if (C < bC || (C == bC && j < bj)) { bC = C; bj = j; }
        }
    }
#pragma unroll
    for (int o = 1; o <= 32; o <<= 1) {
        float oC = __shfl_xor(bC, o);
        int   oj = __shfl_xor(bj, o);
        if (oC < bC || (oC == bC && oj < bj)) { bC = oC; bj = oj; }
    }
    if (t == 0) { widx[row] = bj; out_idx[row] = (float)bj; }
}

// ---------------- K5: gather z_q, write z_q_st, accumulate loss numerator
__global__ __launch_bounds__(256) void k_out(const float* __restrict__ z,
                                             const float* __restrict__ cb,
                                             const float* __restrict__ m,
                                             const int* __restrict__ widx,
                                             float* __restrict__ out0,
                                             double* __restrict__ accs) {
    __shared__ float T[64 * 65];
    __shared__ float ls[4];
    int tid = threadIdx.x;
    int lhw = tid & 63, grp = tid >> 6;
    int bn = blockIdx.x >> 3, bc = blockIdx.x & 7;
    int n0 = bn * 64, c0 = bc * 64;
    int b = n0 >> 12, hw0 = n0 & 4095;
    const float* zb = z + (size_t)b * CCH * HW + hw0;
#pragma unroll
    for (int i = 0; i < 16; ++i) {
        int cl = grp + 4 * i;
        T[cl * 65 + lhw] = zb[(size_t)(c0 + cl) * HW + lhw];
    }
    __syncthreads();
    float la = 0.0f;
#pragma unroll
    for (int i = 0; i < 16; ++i) {
        int nl = grp + 4 * i;
        int n = n0 + nl;
        float zf = T[lhw * 65 + nl];
        int id = widx[n];
        float zq = cb[(size_t)id * CCH + c0 + lhw];
        float d = zq - zf;
        out0[(size_t)n * CCH + c0 + lhw] = zf + d;
        if (m[n] == 0.0f) la = fmaf(d, d, la);
    }
#pragma unroll
    for (int o = 32; o; o >>= 1) la += __shfl_xor(la, o);
    if ((tid & 63) == 0) ls[tid >> 6] = la;
    __syncthreads();
    if (tid == 0) atomicAdd(&accs[0], (double)(ls[0] + ls[1] + ls[2] + ls[3]));
}

// ---------------- K6: finalize loss = (1 + BETA) * mse
__global__ void k_final(const double* __restrict__ accs, float* __restrict__ outl) {
    double num = accs[0], wsum = accs[1];
    double denom = wsum * 512.0;
    double l1 = num / denom;
    outl[0] = (float)(l1 + 0.25 * l1);
}

extern "C" void kernel_launch(void* const* d_in, const int* in_sizes, int n_in,
                              void* d_out, int out_size, void* d_ws, size_t ws_size,
                              hipStream_t stream) {
    const float* z  = (const float*)d_in[0];
    const float* m  = (const float*)d_in[1];
    const float* cb = (const float*)d_in[2];
    float* out = (float*)d_out;
    char* ws = (char*)d_ws;

    unsigned short* BT   = (unsigned short*)(ws + WS_BT);
    float*  zzp  = (float*)(ws + WS_ZZ);
    float*  bm1  = (float*)(ws + WS_BM1);
    float*  bm2  = (float*)(ws + WS_BM2);
    int*    bi1  = (int*)(ws + WS_BI1);
    int*    widx = (int*)(ws + WS_IDX);
    double* accs = (double*)(ws + WS_ACC);

    float* out0    = out;
    float* outLoss = out + 16777216;
    float* outIdx  = out + 16777217;

    // AT scratch lives in the first 33.5MB of d_out (overwritten later by k_out).
    unsigned short* AT = (unsigned short*)out;

    hipLaunchKernelGGL(k_prep_b, dim3(2048), dim3(256), 0, stream, cb, BT, accs);
    hipLaunchKernelGGL(k_prep_a, dim3(8192), dim3(256), 0, stream, z, AT);
    hipLaunchKernelGGL(k_zz,     dim3(128),  dim3(256), 0, stream, z, zzp);
    hipLaunchKernelGGL(k_wsum,   dim3(32),   dim3(256), 0, stream, m, accs);
    hipLaunchKernelGGL(k_gemm,   dim3(8192), dim3(256), 0, stream, AT, BT, bm1, bm2, bi1);
    hipLaunchKernelGGL(k_rescan, dim3(32768), dim3(64), 0, stream, z, cb, zzp, bm1, bm2, bi1, widx, outIdx);
    hipLaunchKernelGGL(k_out,    dim3(4096), dim3(256), 0, stream, z, cb, m, widx, out0, accs);
    hipLaunchKernelGGL(k_final,  dim3(1),    dim3(1),   0, stream, accs, outLoss);
}